// Round 15
// baseline (71.893 us; speedup 1.0000x reference)
//
#include <hip/hip_runtime.h>
#include <math.h>

#define D_DIM 1280
#define ODIM  510

typedef short bf16x8 __attribute__((ext_vector_type(8)));   // 8 bf16 = 4 VGPRs
typedef float f32x4  __attribute__((ext_vector_type(4)));

// pack two fp32 -> packed bf16 pair (round-half-up) — same arithmetic as R12 prep
__device__ __forceinline__ unsigned pkbf(float a, float b) {
  unsigned ua = __float_as_uint(a), ub = __float_as_uint(b);
  return ((ua + 0x8000u) >> 16) | ((ub + 0x8000u) & 0xffff0000u);
}

// Single fused kernel. out[oi][oj][k] = b[k] + sum_d X[oi+1,d]*X[oj+1,d]*W[d][k],
// symmetric in (oi,oj). Triangle grid: 528 blocks of 16x16 tiles. 4 waves split K
// into quarters of 320. Each wave stages its own 32 rows x k-chunk of RAW fp32 X
// into wave-private LDS (coalesced 16B/lane loads, sub-chunks {128,128,64}), then
// packs MFMA frags per step from LDS + global W. No barriers in the K path.
__global__ __launch_bounds__(256, 2) void pcmd_one(
    const float* __restrict__ X,   // [512][1280]
    const float* __restrict__ W,   // [2560][2] (first 1280 rows = Wp)
    const float* __restrict__ b,   // [2]
    float* __restrict__ out)       // [510][510][2]
{
  __shared__ float sX[4][32][132];     // 67.6 KB: [wave][row(0-15 i,16-31 j)][k-local]
  __shared__ float sR[4][2][16][17];   // 8.7 KB: cross-wave K reduce

  // linear block id -> (bi, bj), bi <= bj
  const int t = (int)blockIdx.x;       // 0..527
  int bi = (int)((65.0 - sqrt(4225.0 - 8.0 * (double)t)) * 0.5);
  {
    int s0 = bi * 32 - (bi * (bi - 1)) / 2;
    if (t < s0) { --bi; }
    int s1 = (bi + 1) * 32 - ((bi + 1) * bi) / 2;
    if (t >= s1) { ++bi; }
  }
  const int start = bi * 32 - (bi * (bi - 1)) / 2;
  const int bj = bi + (t - start);

  const int tid  = threadIdx.x;
  const int lane = tid & 63;
  const int wv   = tid >> 6;           // K-quarter owner
  const int m    = lane & 15;
  const int quad = lane >> 4;
  const int iT = bi * 16, jT = bj * 16;
  const int kq = wv * 320;             // this wave's K-quarter base

  f32x4 acc0 = {0.f, 0.f, 0.f, 0.f};
  f32x4 acc1 = {0.f, 0.f, 0.f, 0.f};

  #pragma unroll 1
  for (int sub = 0; sub < 3; ++sub) {
    const int NS    = (sub == 2) ? 64 : 128;   // k's this sub-chunk
    const int koff  = sub * 128;               // 0,128,256
    const int sh    = (sub == 2) ? 4 : 5;      // log2(NS/4)
    const int msk   = (NS >> 2) - 1;
    const int iters = NS >> 3;                 // float4 tasks per lane: 16 or 8

    // ---- stage 32 rows x NS fp32, wave-private, coalesced 16B/lane ----
    #pragma unroll 4
    for (int it = 0; it < iters; ++it) {
      const int idx = it * 64 + lane;
      const int row = idx >> sh;               // 0..31
      const int c4  = idx & msk;               // float4 column
      int gr = (row < 16 ? iT + row : jT + row - 16) + 1;   // X row = out row + 1
      if (gr > 511) gr = 511;                  // junk rows masked at store
      float4 v = *(const float4*)(X + (size_t)gr * D_DIM + kq + koff + c4 * 4);
      *(float4*)&sX[wv][row][c4 * 4] = v;
    }
    // same-wave ds_write -> ds_read: lgkmcnt ordering, no barrier needed

    // ---- MFMA steps over this sub-chunk (4,4,2) ----
    const int steps = NS >> 5;
    #pragma unroll 2
    for (int s = 0; s < steps; ++s) {
      const int col = s * 32 + quad * 8;       // k-local for this lane's frag
      const float* xi = &sX[wv][m][col];
      const float* xj = &sX[wv][16 + m][col];
      float4 xi0 = *(const float4*)xi, xi1 = *(const float4*)(xi + 4);
      float4 xj0 = *(const float4*)xj, xj1 = *(const float4*)(xj + 4);
      const float* pw = W + 2 * (kq + koff + col);   // (w0,w1) interleaved, L2-hot
      float4 w0 = *(const float4*)(pw +  0);
      float4 w1 = *(const float4*)(pw +  4);
      float4 w2 = *(const float4*)(pw +  8);
      float4 w3 = *(const float4*)(pw + 12);

      union { unsigned u[4]; bf16x8 h; } a0, a1, bb;
      bb.u[0] = pkbf(xj0.x, xj0.y);            bb.u[1] = pkbf(xj0.z, xj0.w);
      bb.u[2] = pkbf(xj1.x, xj1.y);            bb.u[3] = pkbf(xj1.z, xj1.w);
      a0.u[0] = pkbf(xi0.x*w0.x, xi0.y*w0.z);  a0.u[1] = pkbf(xi0.z*w1.x, xi0.w*w1.z);
      a0.u[2] = pkbf(xi1.x*w2.x, xi1.y*w2.z);  a0.u[3] = pkbf(xi1.z*w3.x, xi1.w*w3.z);
      a1.u[0] = pkbf(xi0.x*w0.y, xi0.y*w0.w);  a1.u[1] = pkbf(xi0.z*w1.y, xi0.w*w1.w);
      a1.u[2] = pkbf(xi1.x*w2.y, xi1.y*w2.w);  a1.u[3] = pkbf(xi1.z*w3.y, xi1.w*w3.w);

      acc0 = __builtin_amdgcn_mfma_f32_16x16x32_bf16(a0.h, bb.h, acc0, 0, 0, 0);
      acc1 = __builtin_amdgcn_mfma_f32_16x16x32_bf16(a1.h, bb.h, acc1, 0, 0, 0);
    }
  }

  // ---- cross-wave K reduce + symmetric store ----
  // C/D layout: col = lane&15 (j), row = quad*4 + reg (i)  [verified m89/m91]
  #pragma unroll
  for (int r = 0; r < 4; ++r) {
    sR[wv][0][quad * 4 + r][m] = acc0[r];
    sR[wv][1][quad * 4 + r][m] = acc1[r];
  }
  __syncthreads();

  const float b0 = b[0], b1 = b[1];
  const int il = tid >> 4, jl = tid & 15;

  // direct tile: coalesced over jl
  {
    const int oi = iT + il, oj = jT + jl;
    if (oi < ODIM && oj < ODIM) {
      float2 v;
      v.x = sR[0][0][il][jl] + sR[1][0][il][jl] + sR[2][0][il][jl] + sR[3][0][il][jl] + b0;
      v.y = sR[0][1][il][jl] + sR[1][1][il][jl] + sR[2][1][il][jl] + sR[3][1][il][jl] + b1;
      *(float2*)(out + ((size_t)oi * ODIM + oj) * 2) = v;
    }
  }
  // transposed tile (off-diagonal only); LDS stride 17 -> conflict-free
  if (bi != bj) {
    const int oi = jT + il, oj = iT + jl;
    if (oi < ODIM && oj < ODIM) {
      float2 v;
      v.x = sR[0][0][jl][il] + sR[1][0][jl][il] + sR[2][0][jl][il] + sR[3][0][jl][il] + b0;
      v.y = sR[0][1][jl][il] + sR[1][1][jl][il] + sR[2][1][jl][il] + sR[3][1][jl][il] + b1;
      *(float2*)(out + ((size_t)oi * ODIM + oj) * 2) = v;
    }
  }
}

extern "C" void kernel_launch(void* const* d_in, const int* in_sizes, int n_in,
                              void* d_out, int out_size, void* d_ws, size_t ws_size,
                              hipStream_t stream) {
  const float* X = (const float*)d_in[0];
  const float* W = (const float*)d_in[1];
  const float* b = (const float*)d_in[2];
  float* out = (float*)d_out;
  (void)in_sizes; (void)n_in; (void)out_size; (void)d_ws; (void)ws_size;

  hipLaunchKernelGGL(pcmd_one, dim3(528), dim3(256), 0, stream, X, W, b, out);
}

// Round 16
// 70.688 us; speedup vs baseline: 1.0170x; 1.0170x over previous
//
#include <hip/hip_runtime.h>
#include <math.h>

#define D_DIM 1280
#define ODIM  510
#define KSTEPS 40           // 1280 / 32
#define QK    320           // d's per prep K-quarter

typedef short bf16x8 __attribute__((ext_vector_type(8)));   // 8 bf16 = 4 VGPRs
typedef float f32x4  __attribute__((ext_vector_type(4)));

// pack two fp32 -> packed bf16 pair (round-half-up)
__device__ __forceinline__ unsigned pkbf(float a, float b) {
  unsigned ua = __float_as_uint(a), ub = __float_as_uint(b);
  return ((ua + 0x8000u) >> 16) | ((ub + 0x8000u) & 0xffff0000u);
}

// Prep (unchanged from R12): fragment-ordered bf16 planes via LDS transpose;
// both global sides coalesced. Granule (R,K,quad,m) holds plane[R*16+m][K*32+quad*8..+8];
// plane row r = X row r+1 (row 511 zero).
__global__ __launch_bounds__(256, 1) void pcmd_prep(
    const float* __restrict__ X,        // [512][1280]
    const float* __restrict__ W,        // [2560][2] (first 1280 rows = Wp)
    unsigned short* __restrict__ Xbf,
    unsigned short* __restrict__ A0,
    unsigned short* __restrict__ A1)
{
  __shared__ unsigned short sG[3][10][64][8];   // 30 KB

  const int R   = (int)blockIdx.x >> 2;   // row-block 0..31
  const int q   = (int)blockIdx.x & 3;    // K-quarter 0..3
  const int tid = threadIdx.x;

  for (int task = tid; task < 640; task += 256) {
    const int lr = task / 40;
    const int gc = task - lr * 40;
    const int s = gc >> 2, quad = gc & 3;
    const int prow = R * 16 + lr;
    uint4 vx = {0,0,0,0}, v0 = {0,0,0,0}, v1 = {0,0,0,0};
    if (prow <= 510) {
      const float* px = X + (size_t)(prow + 1) * D_DIM + q * QK + gc * 8;
      float4 x0 = *(const float4*)px;
      float4 x1 = *(const float4*)(px + 4);
      const float* pw = W + 2 * (q * QK + gc * 8);
      float4 w0 = *(const float4*)(pw +  0);
      float4 w1 = *(const float4*)(pw +  4);
      float4 w2 = *(const float4*)(pw +  8);
      float4 w3 = *(const float4*)(pw + 12);
      vx.x = pkbf(x0.x, x0.y);            vx.y = pkbf(x0.z, x0.w);
      vx.z = pkbf(x1.x, x1.y);            vx.w = pkbf(x1.z, x1.w);
      v0.x = pkbf(x0.x*w0.x, x0.y*w0.z);  v0.y = pkbf(x0.z*w1.x, x0.w*w1.z);
      v0.z = pkbf(x1.x*w2.x, x1.y*w2.z);  v0.w = pkbf(x1.z*w3.x, x1.w*w3.z);
      v1.x = pkbf(x0.x*w0.y, x0.y*w0.w);  v1.y = pkbf(x0.z*w1.y, x0.w*w1.w);
      v1.z = pkbf(x1.x*w2.y, x1.y*w2.w);  v1.w = pkbf(x1.z*w3.y, x1.w*w3.w);
    }
    const int swzl = quad * 16 + ((lr + quad + 4 * s) & 15);
    *(uint4*)&sG[0][s][swzl][0] = vx;
    *(uint4*)&sG[1][s][swzl][0] = v0;
    *(uint4*)&sG[2][s][swzl][0] = v1;
  }
  __syncthreads();

  for (int g = tid; g < 640; g += 256) {
    const int s = g >> 6, l = g & 63;
    const int quad = l >> 4, m = l & 15;
    const int swzl = quad * 16 + ((m + quad + 4 * s) & 15);
    const size_t go = ((size_t)((R * KSTEPS + q * 10 + s) * 64) + l) * 8;
    *(uint4*)(Xbf + go) = *(const uint4*)&sG[0][s][swzl][0];
    *(uint4*)(A0  + go) = *(const uint4*)&sG[1][s][swzl][0];
    *(uint4*)(A1  + go) = *(const uint4*)&sG[2][s][swzl][0];
  }
}

// GEMM v3: 512-thread blocks, 8 waves split K into EIGHTHS (5 steps each, fully
// preloaded -> 15 loads in flight per wave). 528 triangle blocks x 8 waves = 4224
// waves (~52% occupancy, 2x R12). LDS reduce over 8 partials; epilogue: threads
// 0-255 direct tile, 256-511 transposed tile.
__global__ __launch_bounds__(512, 4) void pcmd_gemm(
    const unsigned short* __restrict__ Xbf,
    const unsigned short* __restrict__ A0,
    const unsigned short* __restrict__ A1,
    const float* __restrict__ b,
    float* __restrict__ out)            // [510][510][2]
{
  __shared__ float sR[8][2][16][17];    // 17.4 KB

  const int t = (int)blockIdx.x;        // 0..527
  int bi = (int)((65.0 - sqrt(4225.0 - 8.0 * (double)t)) * 0.5);
  {
    int s0 = bi * 32 - (bi * (bi - 1)) / 2;
    if (t < s0) { --bi; }
    int s1 = (bi + 1) * 32 - ((bi + 1) * bi) / 2;
    if (t >= s1) { ++bi; }
  }
  const int start = bi * 32 - (bi * (bi - 1)) / 2;
  const int bj = bi + (t - start);

  const int tid  = threadIdx.x;
  const int lane = tid & 63;
  const int wv   = tid >> 6;            // K-eighth owner, 0..7

  // lane-linear fragment pointers; this wave's 5 steps start at granule-step wv*5
  const unsigned short* pa0 = A0  + ((size_t)(bi * KSTEPS + wv * 5) * 64 + lane) * 8;
  const unsigned short* pa1 = A1  + ((size_t)(bi * KSTEPS + wv * 5) * 64 + lane) * 8;
  const unsigned short* pb  = Xbf + ((size_t)(bj * KSTEPS + wv * 5) * 64 + lane) * 8;

  // fully preload all 5 steps (15 x 1KB wave-loads in flight)
  bf16x8 ra0[5], ra1[5], rb[5];
  #pragma unroll
  for (int s = 0; s < 5; ++s) {
    ra0[s] = *(const bf16x8*)(pa0 + s * 512);
    ra1[s] = *(const bf16x8*)(pa1 + s * 512);
    rb[s]  = *(const bf16x8*)(pb  + s * 512);
  }

  f32x4 acc0 = {0.f, 0.f, 0.f, 0.f};
  f32x4 acc1 = {0.f, 0.f, 0.f, 0.f};
  #pragma unroll
  for (int s = 0; s < 5; ++s) {
    acc0 = __builtin_amdgcn_mfma_f32_16x16x32_bf16(ra0[s], rb[s], acc0, 0, 0, 0);
    acc1 = __builtin_amdgcn_mfma_f32_16x16x32_bf16(ra1[s], rb[s], acc1, 0, 0, 0);
  }

  // C/D layout: col = lane&15 (j), row = quad*4 + reg (i)  [verified m89/m91]
  const int m = lane & 15, quad = lane >> 4;
  #pragma unroll
  for (int r = 0; r < 4; ++r) {
    sR[wv][0][quad * 4 + r][m] = acc0[r];
    sR[wv][1][quad * 4 + r][m] = acc1[r];
  }
  __syncthreads();

  const float b0 = b[0], b1 = b[1];

  if (tid < 256) {
    // direct tile: coalesced over jl
    const int il = tid >> 4, jl = tid & 15;
    const int oi = bi * 16 + il, oj = bj * 16 + jl;
    if (oi < ODIM && oj < ODIM) {
      float2 v; v.x = b0; v.y = b1;
      #pragma unroll
      for (int w = 0; w < 8; ++w) { v.x += sR[w][0][il][jl]; v.y += sR[w][1][il][jl]; }
      *(float2*)(out + ((size_t)oi * ODIM + oj) * 2) = v;
    }
  } else if (bi != bj) {
    // transposed tile; LDS stride 17 -> conflict-free
    const int tt = tid - 256;
    const int il = tt >> 4, jl = tt & 15;
    const int oi = bj * 16 + il, oj = bi * 16 + jl;
    if (oi < ODIM && oj < ODIM) {
      float2 v; v.x = b0; v.y = b1;
      #pragma unroll
      for (int w = 0; w < 8; ++w) { v.x += sR[w][0][jl][il]; v.y += sR[w][1][jl][il]; }
      *(float2*)(out + ((size_t)oi * ODIM + oj) * 2) = v;
    }
  }
}

extern "C" void kernel_launch(void* const* d_in, const int* in_sizes, int n_in,
                              void* d_out, int out_size, void* d_ws, size_t ws_size,
                              hipStream_t stream) {
  const float* X = (const float*)d_in[0];
  const float* W = (const float*)d_in[1];
  const float* b = (const float*)d_in[2];
  float* out = (float*)d_out;
  (void)in_sizes; (void)n_in; (void)out_size; (void)ws_size;

  const size_t PLANE = (size_t)512 * D_DIM;        // elements per bf16 plane
  unsigned short* Xbf = (unsigned short*)d_ws;
  unsigned short* A0  = Xbf + PLANE;
  unsigned short* A1  = A0 + PLANE;

  hipLaunchKernelGGL(pcmd_prep, dim3(128), dim3(256), 0, stream, X, W, Xbf, A0, A1);
  hipLaunchKernelGGL(pcmd_gemm, dim3(528), dim3(512), 0, stream, Xbf, A0, A1, b, out);
}